// Round 13
// baseline (645.180 us; speedup 1.0000x reference)
//
#include <hip/hip_runtime.h>
#include <math.h>

#define NN   50000
#define TT   16
#define EE   800000
#define BB   2000
#define EMBD 32
#define ENC  64
#define DEC  128
#define OUTL 25
#define BN_EPS 1e-5f

typedef short v8s __attribute__((ext_vector_type(8)));
typedef float v4f __attribute__((ext_vector_type(4)));
#define MFMA16(a,b,c) __builtin_amdgcn_mfma_f32_16x16x32_bf16((a),(b),(c),0,0,0)

__device__ __forceinline__ float lrelu(float v){ return v >= 0.f ? v : 0.1f*v; }
__device__ __forceinline__ float fsig(float v){ return __builtin_amdgcn_rcpf(1.f + __expf(-v)); }
__device__ __forceinline__ float ftanh(float v){ return 2.f*__builtin_amdgcn_rcpf(1.f + __expf(-2.f*v)) - 1.f; }
__device__ __forceinline__ float fsoftplus(float v){
    return v > 15.f ? v : __logf(1.f + __expf(v));
}
__device__ __forceinline__ float hsum(float4 a){ return (a.x+a.y)+(a.z+a.w); }

__device__ __forceinline__ unsigned short f2bf(float f){
    unsigned u = __float_as_uint(f);
    u = u + 0x7FFFu + ((u>>16)&1u);
    return (unsigned short)(u>>16);
}
__device__ __forceinline__ float bf2f(unsigned short s){ return __uint_as_float(((unsigned)s)<<16); }

__device__ __forceinline__ v8s as_v8s(int4 v){
    union { int4 i; v8s s; } u; u.i = v; return u.s;
}

__device__ __forceinline__ void cvt8(const float* p, v8s& hi, v8s& lo){
    float4 a0 = *(const float4*)p;
    float4 a1 = *(const float4*)(p+4);
    float av[8] = {a0.x,a0.y,a0.z,a0.w,a1.x,a1.y,a1.z,a1.w};
#pragma unroll
    for (int j=0;j<8;j++){
        unsigned short h = f2bf(av[j]);
        hi[j] = (short)h;
        lo[j] = (short)f2bf(av[j] - bf2f(h));
    }
}
// reconstruct hi+lo, lrelu, re-split
__device__ __forceinline__ void lrelu_resplit(v8s hh, v8s hl, v8s& oh, v8s& ol){
#pragma unroll
    for (int j=0;j<8;j++){
        float v = bf2f((unsigned short)hh[j]) + bf2f((unsigned short)hl[j]);
        float a = lrelu(v);
        unsigned short h = f2bf(a);
        oh[j] = (short)h;
        ol[j] = (short)f2bf(a - bf2f(h));
    }
}

// ---------------- fused packing helpers ----------------
__device__ __forceinline__ void pf_item(const float* W, int K, int KB, int i,
                                        unsigned short* out){
    int l = i & 63, fb = i >> 6;
    int kb = fb % KB, nt = fb / KB;
    int n = nt*16 + (l&15);
    int k0 = kb*32 + ((l>>4)*8);
#pragma unroll
    for (int j=0;j<8;j++) out[i*8+j] = f2bf(W[(size_t)n*K + k0 + j]);
}
__device__ __forceinline__ void phl_item(const float* W, int K, int KB, int i,
                                         unsigned short* hi, unsigned short* lo){
    int l = i & 63, fb = i >> 6;
    int kb = fb % KB, nt = fb / KB;
    int n = nt*16 + (l&15);
    int k0 = kb*32 + ((l>>4)*8);
#pragma unroll
    for (int j=0;j<8;j++){
        float v = W[(size_t)n*K + k0 + j];
        unsigned short h = f2bf(v);
        hi[i*8+j] = h;
        lo[i*8+j] = f2bf(v - bf2f(h));
    }
}
__device__ __forceinline__ void pcat_item(const float* Wa, const float* Wb,
                                          int K1, int K, int KB, int i,
                                          unsigned short* out){
    int l = i & 63, fb = i >> 6;
    int kb = fb % KB, nt = fb / KB;
    int n = nt*16 + (l&15);
    int k0 = kb*32 + ((l>>4)*8);
#pragma unroll
    for (int j=0;j<8;j++){
        int k = k0 + j;
        float v = (k < K1) ? Wa[(size_t)n*K1 + k] : Wb[(size_t)n*(K-K1) + (k-K1)];
        out[i*8+j] = f2bf(v);
    }
}
__device__ __forceinline__ void pproj_item(const float* Wf, const float* Ws, int i,
                                           unsigned short* hi, unsigned short* lo){
    int l = i & 63, fb = i >> 6;
    int kb = fb & 1, nt = fb >> 1;
    int n = nt*16 + (l&15);
    int d = n >> 6, c = n & 63;
    const float* W = (d < 2) ? Wf : Ws;
    int k0 = (d&1)*64 + kb*32 + ((l>>4)*8);
#pragma unroll
    for (int j=0;j<8;j++){
        float v = W[c*130 + k0 + j];
        unsigned short h = f2bf(v);
        hi[i*8+j] = h;
        lo[i*8+j] = f2bf(v - bf2f(h));
    }
}

// ---------------- all weight prep in ONE dispatch ----------------
__global__ void pack_all(
    const float* __restrict__ gWih, const float* __restrict__ gWhh,
    const float* __restrict__ Wdyn,
    const float* __restrict__ l0Whh, const float* __restrict__ l1Wih,
    const float* __restrict__ l1Whh, const float* __restrict__ l0Wih,
    const float* __restrict__ c1Wf, const float* __restrict__ c1Ws,
    const float* __restrict__ c2Wf, const float* __restrict__ c2Ws,
    unsigned short* __restrict__ pWih, unsigned short* __restrict__ pWhh,
    unsigned short* __restrict__ pWdyn,
    unsigned short* __restrict__ B0h, unsigned short* __restrict__ B1h,
    unsigned short* __restrict__ P1h, unsigned short* __restrict__ P1l,
    unsigned short* __restrict__ P2h, unsigned short* __restrict__ P2l,
    unsigned short* __restrict__ GIh, unsigned short* __restrict__ GIl,
    int* __restrict__ cnt, int* __restrict__ gtot)
{
    int i = blockIdx.x*256 + threadIdx.x;
    if (i < 768){ pf_item(gWih, 32, 1, i, pWih); return; }   i -= 768;
    if (i < 1536){ pf_item(gWhh, 64, 2, i, pWhh); return; }  i -= 1536;
    if (i < 512){ pf_item(Wdyn, 64, 2, i, pWdyn); return; }  i -= 512;
    if (i < 8192){ pcat_item(l0Whh, l0Whh, 128, 128, 4, i, B0h); return; } i -= 8192;
    if (i < 16384){ pcat_item(l1Wih, l1Whh, 128, 256, 8, i, B1h); return; } i -= 16384;
    if (i < 2048){ pproj_item(c1Wf, c1Ws, i, P1h, P1l); return; } i -= 2048;
    if (i < 2048){ pproj_item(c2Wf, c2Ws, i, P2h, P2l); return; } i -= 2048;
    if (i < 8192){ phl_item(l0Wih, 128, 4, i, GIh, GIl); return; } i -= 8192;
    if (i < NN){ cnt[i] = 0; return; } i -= NN;
    if (i < 1){ gtot[0] = 0; return; }
}
#define PACK_TOTAL (768+1536+512+8192+16384+2048+2048+8192+NN+1)

// ---------------- GRU encoder v5 ----------------
// R12 post-mortem: 114us at Occ 18% — latency-bound serial t-loop: 2 barriers/
// step, 21 unhoisted B-frag L2 loads/step (VGPR=104: compiler remat, same as
// R7 lstm), emb VALU inside the loop. v5 (the lstm playbook): (1) 22 weight
// frags pinned in regs (88 VGPRs, waves_per_eu(2,2)); (2) ALL 16 steps of emb
// frags precomputed before the loop (32KB LDS); (3) h frags double-buffered ->
// ONE barrier/step; (4) dual hi/lo accumulators (3-deep MFMA chains).
__global__ __launch_bounds__(128)
__attribute__((amdgpu_waves_per_eu(2,2)))
void encoder_mfma(
    const float* __restrict__ x,
    const float* __restrict__ Wip, const float* __restrict__ bip,
    const unsigned short* __restrict__ pWih,
    const unsigned short* __restrict__ pWhh,
    const float* __restrict__ bih, const float* __restrict__ bhh,
    const unsigned short* __restrict__ pWdyn,
    const float* __restrict__ bdyn,
    float* __restrict__ hist)
{
    __shared__ float sxl[512];                           // 2 KB
    __shared__ unsigned short efh[16*512], efl[16*512];  // 32 KB: emb frags, all steps
    __shared__ unsigned short hfh[2][1024], hfl[2][1024];// 8 KB: h frags, dbuf
    const int tid = threadIdx.x;
    const int l   = tid & 63;
    const int w   = tid >> 6;
    const int ln  = l & 15, q = l >> 4;
    const int blk = blockIdx.x;

    ((float4*)sxl)[tid] = ((const float4*)x)[(size_t)blk*128 + tid];
    {
        unsigned short* ph = &hfh[0][0];
        unsigned short* pl = &hfl[0][0];
        for (int i=tid;i<2048;i+=128){ ph[i]=0; pl[i]=0; }
    }

    const int ek = tid & 31;
    const float w0 = Wip[2*ek], w1 = Wip[2*ek+1], bk = bip[ek];
    const int em0 = tid >> 5;
    const int eoffb = (16*(ek>>3))*8 + (ek&7);

    float bR[2], bZ[2], bNI[2], bNH[2];
    float hprev[2][4];
#pragma unroll
    for (int u=0;u<2;u++){
        int g = 2*w + u;
        int c = g*16 + ln;
        bR[u]  = bih[c]       + bhh[c];
        bZ[u]  = bih[64 + c]  + bhh[64 + c];
        bNI[u] = bih[128 + c];
        bNH[u] = bhh[128 + c];
        hprev[u][0]=0.f; hprev[u][1]=0.f; hprev[u][2]=0.f; hprev[u][3]=0.f;
    }

    // ---- pinned weight fragments: 22 int4 = 88 VGPRs ----
    int4 WI[2][3], WH[2][6], WD[2][2];
    {
        const int4* FIH = (const int4*)pWih;
        const int4* FHH = (const int4*)pWhh;
        const int4* FDY = (const int4*)pWdyn;
#pragma unroll
        for (int u=0;u<2;u++){
            int g = 2*w + u;
            WI[u][0] = FIH[(g    )*64 + l];
            WI[u][1] = FIH[(4 + g)*64 + l];
            WI[u][2] = FIH[(8 + g)*64 + l];
            WH[u][0] = FHH[((g    )*2+0)*64 + l];
            WH[u][1] = FHH[((g    )*2+1)*64 + l];
            WH[u][2] = FHH[((4 + g)*2+0)*64 + l];
            WH[u][3] = FHH[((4 + g)*2+1)*64 + l];
            WH[u][4] = FHH[((8 + g)*2+0)*64 + l];
            WH[u][5] = FHH[((8 + g)*2+1)*64 + l];
            WD[u][0] = FDY[((2*w+u)*2+0)*64 + l];
            WD[u][1] = FDY[((2*w+u)*2+1)*64 + l];
        }
#pragma unroll
        for (int u=0;u<2;u++){
#pragma unroll
            for (int i=0;i<3;i++)
                asm volatile("" : "+v"(WI[u][i].x), "+v"(WI[u][i].y), "+v"(WI[u][i].z), "+v"(WI[u][i].w));
#pragma unroll
            for (int i=0;i<6;i++)
                asm volatile("" : "+v"(WH[u][i].x), "+v"(WH[u][i].y), "+v"(WH[u][i].z), "+v"(WH[u][i].w));
#pragma unroll
            for (int i=0;i<2;i++)
                asm volatile("" : "+v"(WD[u][i].x), "+v"(WD[u][i].y), "+v"(WD[u][i].z), "+v"(WD[u][i].w));
        }
    }
    __syncthreads();    // sxl + h zeros visible

    // ---- precompute emb frags for ALL timesteps (h-independent) ----
#pragma unroll 1
    for (int t=0;t<TT;t++){
#pragma unroll
        for (int r=0;r<4;r++){
            int m = em0 + r*4;
            float e = lrelu(w0*sxl[m*32 + 2*t] + w1*sxl[m*32 + 2*t + 1] + bk);
            unsigned short h_ = f2bf(e);
            int off = t*512 + eoffb + m*8;
            efh[off] = h_;
            efl[off] = f2bf(e - bf2f(h_));
        }
    }
    __syncthreads();    // emb frags ready

    int p = 0;
#pragma unroll 1
    for (int t=0;t<TT;t++){
        v8s eh  = *(const v8s*)&efh[t*512 + l*8];
        v8s el  = *(const v8s*)&efl[t*512 + l*8];
        v8s h0h = *(const v8s*)&hfh[p][l*8];
        v8s h0l = *(const v8s*)&hfl[p][l*8];
        v8s h1h = *(const v8s*)&hfh[p][512 + l*8];
        v8s h1l = *(const v8s*)&hfl[p][512 + l*8];
#pragma unroll
        for (int u=0;u<2;u++){
            int g = 2*w + u;
            v4f aRh = {bR[u],bR[u],bR[u],bR[u]},   aRl = {0.f,0.f,0.f,0.f};
            v4f aZh = {bZ[u],bZ[u],bZ[u],bZ[u]},   aZl = {0.f,0.f,0.f,0.f};
            v4f aNIh= {bNI[u],bNI[u],bNI[u],bNI[u]},aNIl= {0.f,0.f,0.f,0.f};
            v4f aNHh= {bNH[u],bNH[u],bNH[u],bNH[u]},aNHl= {0.f,0.f,0.f,0.f};
            aRh = MFMA16(eh,  as_v8s(WI[u][0]), aRh);
            aRl = MFMA16(el,  as_v8s(WI[u][0]), aRl);
            aRh = MFMA16(h0h, as_v8s(WH[u][0]), aRh);
            aRl = MFMA16(h0l, as_v8s(WH[u][0]), aRl);
            aRh = MFMA16(h1h, as_v8s(WH[u][1]), aRh);
            aRl = MFMA16(h1l, as_v8s(WH[u][1]), aRl);
            aZh = MFMA16(eh,  as_v8s(WI[u][1]), aZh);
            aZl = MFMA16(el,  as_v8s(WI[u][1]), aZl);
            aZh = MFMA16(h0h, as_v8s(WH[u][2]), aZh);
            aZl = MFMA16(h0l, as_v8s(WH[u][2]), aZl);
            aZh = MFMA16(h1h, as_v8s(WH[u][3]), aZh);
            aZl = MFMA16(h1l, as_v8s(WH[u][3]), aZl);
            aNIh= MFMA16(eh,  as_v8s(WI[u][2]), aNIh);
            aNIl= MFMA16(el,  as_v8s(WI[u][2]), aNIl);
            aNHh= MFMA16(h0h, as_v8s(WH[u][4]), aNHh);
            aNHl= MFMA16(h0l, as_v8s(WH[u][4]), aNHl);
            aNHh= MFMA16(h1h, as_v8s(WH[u][5]), aNHh);
            aNHl= MFMA16(h1l, as_v8s(WH[u][5]), aNHl);
#pragma unroll
            for (int i=0;i<4;i++){
                float r_ = fsig(aRh[i]+aRl[i]);
                float z_ = fsig(aZh[i]+aZl[i]);
                float nn_ = ftanh(aNIh[i]+aNIl[i] + r_*(aNHh[i]+aNHl[i]));
                float hn = (1.f - z_)*nn_ + z_*hprev[u][i];
                hprev[u][i] = hn;
                int row = q*4 + i, col = g*16 + ln;
                int off = (col>>5)*512 + (16*((col&31)>>3) + row)*8 + (col&7);
                unsigned short hh_ = f2bf(hn);
                hfh[1-p][off] = hh_;
                hfl[1-p][off] = f2bf(hn - bf2f(hh_));
            }
        }
        __syncthreads();    // the ONLY barrier per step
        p ^= 1;
    }
    // ---- hist = lrelu(lrelu(h) @ Wdyn^T + b) ----
    {
        v8s a0h,a0l,a1h,a1l;
        lrelu_resplit(*(const v8s*)&hfh[p][l*8],       *(const v8s*)&hfl[p][l*8],       a0h, a0l);
        lrelu_resplit(*(const v8s*)&hfh[p][512 + l*8], *(const v8s*)&hfl[p][512 + l*8], a1h, a1l);
#pragma unroll
        for (int u=0;u<2;u++){
            int nt = 2*w + u;
            float bb = bdyn[nt*16 + ln];
            v4f acc = {bb,bb,bb,bb};
            acc = MFMA16(a0h, as_v8s(WD[u][0]), acc);
            acc = MFMA16(a0l, as_v8s(WD[u][0]), acc);
            acc = MFMA16(a1h, as_v8s(WD[u][1]), acc);
            acc = MFMA16(a1l, as_v8s(WD[u][1]), acc);
#pragma unroll
            for (int i=0;i<4;i++){
                hist[(size_t)(blk*16 + q*4 + i)*64 + nt*16 + ln] = lrelu(acc[i]);
            }
        }
    }
}

// ---------------- CGConv projections: MFMA (unchanged) ----------------
__global__ __launch_bounds__(256) void proj_mfma(
    const float* __restrict__ xin,
    const unsigned short* __restrict__ Bh, const unsigned short* __restrict__ Bl,
    float* __restrict__ Af, float* __restrict__ Bf,
    float* __restrict__ As, float* __restrict__ Bs)
{
    __shared__ float sx[64*68];
    const int tid = threadIdx.x;
    const int l = tid & 63;
    const int w = tid >> 6;
    const int ln = l & 15, q = l >> 4;
    const int n0 = blockIdx.x*64;

    for (int i=tid;i<64*16;i+=256){
        int nn = i>>4, f4 = i&15;
        float4 v = {0.f,0.f,0.f,0.f};
        if (n0+nn < NN) v = ((const float4*)(xin + (size_t)(n0+nn)*64))[f4];
        *(float4*)&sx[nn*68 + f4*4] = v;
    }
    __syncthreads();

    v8s ah0,al0,ah1,al1;
    cvt8(&sx[(w*16+ln)*68 +      q*8], ah0, al0);
    cvt8(&sx[(w*16+ln)*68 + 32 + q*8], ah1, al1);

    const v8s* FH = (const v8s*)Bh;
    const v8s* FL = (const v8s*)Bl;
#pragma unroll 1
    for (int nt=0; nt<16; nt++){
        v8s bh0 = FH[(nt*2+0)*64 + l], bl0 = FL[(nt*2+0)*64 + l];
        v8s bh1 = FH[(nt*2+1)*64 + l], bl1 = FL[(nt*2+1)*64 + l];
        v4f acc = {0.f,0.f,0.f,0.f};
        acc = MFMA16(ah0,bh0,acc); acc = MFMA16(al0,bh0,acc); acc = MFMA16(ah0,bl0,acc);
        acc = MFMA16(ah1,bh1,acc); acc = MFMA16(al1,bh1,acc); acc = MFMA16(ah1,bl1,acc);
        int d = nt >> 2, col = (nt&3)*16 + ln;
        float* op = (d==0) ? Af : (d==1) ? Bf : (d==2) ? As : Bs;
#pragma unroll
        for (int i=0;i<4;i++){
            int node = n0 + w*16 + q*4 + i;
            if (node < NN) op[(size_t)node*64 + col] = acc[i];
        }
    }
}

// ---------------- dst segment build: histogram + atomic alloc + scatter ----------------
__global__ void count_kernel(const int* __restrict__ ei, int* __restrict__ cnt){
    int e = blockIdx.x*256 + threadIdx.x;
    if (e < EE) atomicAdd(&cnt[ei[EE+e]], 1);
}

__global__ void alloc_kernel(const int* __restrict__ cnt, int* __restrict__ gtot,
                             int* __restrict__ off, int* __restrict__ cur){
    int n = blockIdx.x*256 + threadIdx.x;
    if (n >= NN) return;
    int c = cnt[n];
    int s = atomicAdd(gtot, c);
    off[n] = s;
    cur[n] = s;
}

// scatter + pre-gather (src, e0, e1) into ONE int4 record per edge
__global__ void scatter_kernel(const int* __restrict__ ei, const float* __restrict__ ea,
                               int* __restrict__ cur, int4* __restrict__ recS){
    int e = blockIdx.x*256 + threadIdx.x;
    if (e >= EE) return;
    int d = ei[EE+e];
    int p = atomicAdd(&cur[d], 1);
    int4 r;
    r.x = ei[e];
    r.y = __float_as_int(ea[2*(size_t)e]);
    r.z = __float_as_int(ea[2*(size_t)e+1]);
    r.w = 0;
    recS[p] = r;
}

// ---------------- CGConv aggregate (packed records) ----------------
__global__ __launch_bounds__(256) void cg_agg(
    const float* __restrict__ xin,
    const int4* __restrict__ recS,
    const int* __restrict__ off, const int* __restrict__ cnt,
    const float* __restrict__ Wf, const float* __restrict__ bf,
    const float* __restrict__ Ws, const float* __restrict__ bs,
    const float* __restrict__ Af, const float* __restrict__ Bf,
    const float* __restrict__ As, const float* __restrict__ Bs,
    const float* __restrict__ gamma, const float* __restrict__ beta,
    const float* __restrict__ mean, const float* __restrict__ var,
    float* __restrict__ outp)
{
    const int tid = threadIdx.x;
    const int c = tid & 63, wid = tid >> 6;
    const int n = blockIdx.x*4 + wid;
    if (n >= NN) return;

    const float wf0 = Wf[c*130+128], wf1 = Wf[c*130+129], bfc = bf[c];
    const float ws0 = Ws[c*130+128], ws1 = Ws[c*130+129], bsc = bs[c];
    const float afd = Af[(size_t)n*64+c] + bfc, asd = As[(size_t)n*64+c] + bsc;
    const float* Bfc = Bf + c;
    const float* Bsc = Bs + c;

    float acc = 0.f;
    int i = off[n];
    const int i1 = i + cnt[n];
#pragma unroll 1
    for (; i+1 < i1; i += 2){
        int4 r0 = recS[i], r1 = recS[i+1];
        float e00 = __int_as_float(r0.y), e01 = __int_as_float(r0.z);
        float e10 = __int_as_float(r1.y), e11 = __int_as_float(r1.z);
        float bf0v = Bfc[(size_t)r0.x*64], bs0v = Bsc[(size_t)r0.x*64];
        float bf1v = Bfc[(size_t)r1.x*64], bs1v = Bsc[(size_t)r1.x*64];
        float gf0 = afd + bf0v + wf0*e00 + wf1*e01;
        float gs0 = asd + bs0v + ws0*e00 + ws1*e01;
        float gf1 = afd + bf1v + wf0*e10 + wf1*e11;
        float gs1 = asd + bs1v + ws0*e10 + ws1*e11;
        acc += fsig(gf0)*fsoftplus(gs0);
        acc += fsig(gf1)*fsoftplus(gs1);
    }
    if (i < i1){
        int4 r0 = recS[i];
        float e00 = __int_as_float(r0.y), e01 = __int_as_float(r0.z);
        float gf = afd + Bfc[(size_t)r0.x*64] + wf0*e00 + wf1*e01;
        float gs = asd + Bsc[(size_t)r0.x*64] + ws0*e00 + ws1*e01;
        acc += fsig(gf)*fsoftplus(gs);
    }
    float bn = (acc - mean[c])*rsqrtf(var[c]+BN_EPS)*gamma[c] + beta[c];
    outp[(size_t)n*64+c] = xin[(size_t)n*64+c] + bn;
}

// ---------------- target gather + nbrs linear + concat (unchanged) ----------------
__global__ __launch_bounds__(256) void target_kernel(
    const float* __restrict__ hist, const float* __restrict__ f2,
    const int* __restrict__ tgt,
    const float* __restrict__ Wn, const float* __restrict__ bn_,
    float* __restrict__ enc)
{
    const int tid=threadIdx.x;
    const int c = tid&63, q = tid>>6;
    const int b = blockIdx.x*4 + q;
    if (b>=BB) return;
    const int n = tgt[b];
    float a = bn_[c];
#pragma unroll
    for (int k=0;k<ENC;k++) a += Wn[c*64+k]*f2[(size_t)n*64+k];
    enc[(size_t)b*128 + 64 + c] = lrelu(a);
    enc[(size_t)b*128 + c]      = hist[(size_t)n*64+c];
}

// ---------------- gi0 via MFMA (unchanged) ----------------
__global__ __launch_bounds__(512) void gi0_mfma(
    const float* __restrict__ enc,
    const unsigned short* __restrict__ GIh, const unsigned short* __restrict__ GIl,
    const float* __restrict__ bih0, const float* __restrict__ bhh0,
    float* __restrict__ gi0)
{
    __shared__ float senc[16*132];
    const int tid = threadIdx.x;
    const int l = tid & 63;
    const int w = tid >> 6;
    const int ln = l & 15, q = l >> 4;
    const int b0 = blockIdx.x*16;

    for (int i=tid;i<16*32;i+=512){
        int row = i>>5, f4 = i&31;
        *(float4*)&senc[row*132 + f4*4] = ((const float4*)(enc + (size_t)(b0+row)*128))[f4];
    }
    __syncthreads();

    v8s ah[4], al[4];
#pragma unroll
    for (int kb=0;kb<4;kb++) cvt8(&senc[ln*132 + kb*32 + q*8], ah[kb], al[kb]);

    const v8s* FH = (const v8s*)GIh;
    const v8s* FL = (const v8s*)GIl;
#pragma unroll
    for (int u=0;u<4;u++){
        int nt = w*4 + u;
        int col = nt*16 + ln;
        float bb = bih0[col] + bhh0[col];
        v4f acc = {bb,bb,bb,bb};
#pragma unroll
        for (int kb=0;kb<4;kb++){
            v8s bh = FH[(nt*4+kb)*64 + l];
            v8s bl = FL[(nt*4+kb)*64 + l];
            acc = MFMA16(ah[kb],bh,acc); acc = MFMA16(al[kb],bh,acc); acc = MFMA16(ah[kb],bl,acc);
        }
#pragma unroll
        for (int i=0;i<4;i++)
            gi0[(size_t)(b0 + q*4 + i)*512 + col] = acc[i];
    }
}

// ---------------- 2-layer LSTM decoder v7 (unchanged) ----------------
#define LMB 16
__global__ __launch_bounds__(512)
__attribute__((amdgpu_waves_per_eu(2,2)))
void lstm_mfma(
    const float* __restrict__ gi0,
    const unsigned short* __restrict__ B0h,
    const unsigned short* __restrict__ B1h,
    const float* __restrict__ bih1, const float* __restrict__ bhh1,
    const float* __restrict__ Wop, const float* __restrict__ bop,
    float* __restrict__ outp)
{
    __shared__ int4 sW0[32*4*64];                                // 131072 B
    __shared__ unsigned short h0hi[2][4*512], h0lo[2][4*512];    // 16384 B
    __shared__ unsigned short h1hi[2][4*512], h1lo[2][4*512];    // 16384 B
    const int tid = threadIdx.x;
    const int l = tid & 63;
    const int w = tid >> 6;
    const int c = l & 15;
    const int q = l >> 4;
    const int j = w*16 + c;
    const int b0 = blockIdx.x*LMB;

    {
        const int4* F0 = (const int4*)B0h;
        for (int i=tid;i<32*4*64;i+=512) sW0[i] = F0[i];
    }
    for (int i=tid;i<4*512;i+=512){
        h0hi[0][i]=0; h0lo[0][i]=0; h0hi[1][i]=0; h0lo[1][i]=0;
        h1hi[0][i]=0; h1lo[0][i]=0; h1hi[1][i]=0; h1lo[1][i]=0;
    }

    int4 W1r[32];
    {
        const int4* F1 = (const int4*)B1h;
#pragma unroll
        for (int g=0;g<4;g++)
#pragma unroll
            for (int kb=0;kb<8;kb++) W1r[g*8+kb] = F1[((g*8+w)*8 + kb)*64 + l];
#pragma unroll
        for (int i=0;i<32;i++)
            asm volatile("" : "+v"(W1r[i].x), "+v"(W1r[i].y), "+v"(W1r[i].z), "+v"(W1r[i].w));
    }

    float rgi[4][4];
#pragma unroll
    for (int g=0;g<4;g++)
#pragma unroll
        for (int i=0;i<4;i++)
            rgi[g][i] = gi0[(size_t)(b0 + q*4 + i)*512 + g*128 + j];

    float b1[4];
#pragma unroll
    for (int g=0;g<4;g++) b1[g] = bih1[g*128+j] + bhh1[g*128+j];
    float c0[4] = {0,0,0,0}, c1[4] = {0,0,0,0};
    const float wop0 = Wop[j], wop1 = Wop[128 + j];
    const float bo0 = bop[0], bo1 = bop[1];
    const int kbw = j>>5, qw = (j>>3)&3, jw = j&7;
    __syncthreads();

    int p = 0;
#pragma unroll 1
    for (int t=0;t<OUTL;t++){
        v4f aH[4], aL[4];
#pragma unroll
        for (int g=0;g<4;g++){
            v4f t4 = {rgi[g][0], rgi[g][1], rgi[g][2], rgi[g][3]};
            aH[g] = t4;
            v4f z = {0.f,0.f,0.f,0.f};
            aL[g] = z;
        }
#pragma unroll
        for (int kb=0;kb<4;kb++){
            v8s ah = *(const v8s*)&h0hi[p][kb*512 + l*8];
            v8s al = *(const v8s*)&h0lo[p][kb*512 + l*8];
#pragma unroll
            for (int g=0;g<4;g++){
                v8s bfr = as_v8s(sW0[((g*8+w)*4 + kb)*64 + l]);
                aH[g] = MFMA16(ah, bfr, aH[g]);
                aL[g] = MFMA16(al, bfr, aL[g]);
            }
        }
#pragma unroll
        for (int i=0;i<4;i++){
            float gi_ = aH[0][i]+aL[0][i], gf_ = aH[1][i]+aL[1][i];
            float gg_ = aH[2][i]+aL[2][i], go_ = aH[3][i]+aL[3][i];
            c0[i] = fsig(gf_)*c0[i] + fsig(gi_)*ftanh(gg_);
            float hn = fsig(go_)*ftanh(c0[i]);
            int off = kbw*512 + (qw*16 + q*4 + i)*8 + jw;
            unsigned short h = f2bf(hn);
            h0hi[1-p][off] = h;
            h0lo[1-p][off] = f2bf(hn - bf2f(h));
        }
        __syncthreads();   // B1: the ONLY barrier per step

        v4f bH[4], bL[4];
#pragma unroll
        for (int g=0;g<4;g++){
            v4f t4={b1[g],b1[g],b1[g],b1[g]}; bH[g]=t4;
            v4f z={0.f,0.f,0.f,0.f}; bL[g]=z;
        }
#pragma unroll
        for (int kb=0;kb<8;kb++){
            const unsigned short* hb = (kb<4) ? h0hi[1-p] : h1hi[p];
            const unsigned short* lb = (kb<4) ? h0lo[1-p] : h1lo[p];
            int kk = kb & 3;
            v8s ah = *(const v8s*)&hb[kk*512 + l*8];
            v8s al = *(const v8s*)&lb[kk*512 + l*8];
#pragma unroll
            for (int g=0;g<4;g++){
                bH[g] = MFMA16(ah, as_v8s(W1r[g*8+kb]), bH[g]);
                bL[g] = MFMA16(al, as_v8s(W1r[g*8+kb]), bL[g]);
            }
        }
        float h1new[4];
#pragma unroll
        for (int i=0;i<4;i++){
            float gi_ = bH[0][i]+bL[0][i], gf_ = bH[1][i]+bL[1][i];
            float gg_ = bH[2][i]+bL[2][i], go_ = bH[3][i]+bL[3][i];
            c1[i] = fsig(gf_)*c1[i] + fsig(gi_)*ftanh(gg_);
            h1new[i] = fsig(go_)*ftanh(c1[i]);
            int off = kbw*512 + (qw*16 + q*4 + i)*8 + jw;
            unsigned short h = f2bf(h1new[i]);
            h1hi[1-p][off] = h;
            h1lo[1-p][off] = f2bf(h1new[i] - bf2f(h));
        }

        {
            float v0[4], v1[4];
#pragma unroll
            for (int i=0;i<4;i++){ v0[i] = h1new[i]*wop0; v1[i] = h1new[i]*wop1; }
#pragma unroll
            for (int m=1;m<16;m<<=1){
#pragma unroll
                for (int i=0;i<4;i++){
                    v0[i] += __shfl_xor(v0[i], m);
                    v1[i] += __shfl_xor(v1[i], m);
                }
            }
            if (c == 0){
                if (w == 0){
#pragma unroll
                    for (int i=0;i<4;i++){ v0[i] += bo0; v1[i] += bo1; }
                }
#pragma unroll
                for (int i=0;i<4;i++){
                    size_t base = (size_t)(b0 + q*4 + i)*(OUTL*2) + t*2;
                    atomicAdd(&outp[base    ], v0[i]);
                    atomicAdd(&outp[base + 1], v1[i]);
                }
            }
        }
        p ^= 1;
    }
}

extern "C" void kernel_launch(void* const* d_in, const int* in_sizes, int n_in,
                              void* d_out, int out_size, void* d_ws, size_t ws_size,
                              hipStream_t stream)
{
    const float* x    = (const float*)d_in[0];
    const int*   ei   = (const int*)d_in[1];
    const float* ea   = (const float*)d_in[2];
    const int*   tgt  = (const int*)d_in[3];
    const float* Wip  = (const float*)d_in[4];
    const float* bip  = (const float*)d_in[5];
    const float* gWih = (const float*)d_in[6];
    const float* gWhh = (const float*)d_in[7];
    const float* gbih = (const float*)d_in[8];
    const float* gbhh = (const float*)d_in[9];
    const float* Wdyn = (const float*)d_in[10];
    const float* bdyn = (const float*)d_in[11];
    const float* c1Wf=(const float*)d_in[12]; const float* c1bf=(const float*)d_in[13];
    const float* c1Ws=(const float*)d_in[14]; const float* c1bs=(const float*)d_in[15];
    const float* c1g =(const float*)d_in[16]; const float* c1b =(const float*)d_in[17];
    const float* c1m =(const float*)d_in[18]; const float* c1v =(const float*)d_in[19];
    const float* c2Wf=(const float*)d_in[20]; const float* c2bf=(const float*)d_in[21];
    const float* c2Ws=(const float*)d_in[22]; const float* c2bs=(const float*)d_in[23];
    const float* c2g =(const float*)d_in[24]; const float* c2b =(const float*)d_in[25];
    const float* c2m =(const float*)d_in[26]; const float* c2v =(const float*)d_in[27];
    const float* Wn  =(const float*)d_in[28]; const float* bn_ =(const float*)d_in[29];
    const float* l0Wih=(const float*)d_in[30]; const float* l0Whh=(const float*)d_in[31];
    const float* l0bih=(const float*)d_in[32]; const float* l0bhh=(const float*)d_in[33];
    const float* l1Wih=(const float*)d_in[34]; const float* l1Whh=(const float*)d_in[35];
    const float* l1bih=(const float*)d_in[36]; const float* l1bhh=(const float*)d_in[37];
    const float* Wop =(const float*)d_in[38]; const float* bop=(const float*)d_in[39];

    float* ws = (float*)d_ws;
    size_t o = 0;
    float* hist = ws + o; o += (size_t)NN*ENC;
    float* f1   = ws + o; o += (size_t)NN*ENC;
    float* f2   = ws + o; o += (size_t)NN*ENC;
    float* Af   = ws + o; o += (size_t)NN*ENC;
    float* Bf   = ws + o; o += (size_t)NN*ENC;
    float* As   = ws + o; o += (size_t)NN*ENC;
    float* Bs   = ws + o; o += (size_t)NN*ENC;
    float* enc  = ws + o; o += (size_t)BB*2*ENC;
    float* gi0  = ws + o; o += (size_t)BB*4*DEC;
    unsigned short* pWih  = (unsigned short*)(ws + o); o += (size_t)12*64*8/2;
    unsigned short* pWhh  = (unsigned short*)(ws + o); o += (size_t)24*64*8/2;
    unsigned short* pWdyn = (unsigned short*)(ws + o); o += (size_t)8*64*8/2;
    unsigned short* B0h = (unsigned short*)(ws + o); o += (size_t)32*4*64*8/2;
    unsigned short* B1h = (unsigned short*)(ws + o); o += (size_t)32*8*64*8/2;
    unsigned short* P1h = (unsigned short*)(ws + o); o += (size_t)2048*8/2;
    unsigned short* P1l = (unsigned short*)(ws + o); o += (size_t)2048*8/2;
    unsigned short* P2h = (unsigned short*)(ws + o); o += (size_t)2048*8/2;
    unsigned short* P2l = (unsigned short*)(ws + o); o += (size_t)2048*8/2;
    unsigned short* GIh = (unsigned short*)(ws + o); o += (size_t)8192*8/2;
    unsigned short* GIl = (unsigned short*)(ws + o); o += (size_t)8192*8/2;
    int* cnt    = (int*)(ws + o); o += NN;
    int* offv   = (int*)(ws + o); o += NN+1;
    int* curv   = (int*)(ws + o); o += NN;
    int* gtot   = (int*)(ws + o); o += 1;
    o = (o + 3) & ~(size_t)3;               // align to 16B for int4 records
    int4* recS  = (int4*)(ws + o); o += (size_t)4*EE;

    // --- all weight prep + cnt/gtot zero in one dispatch ---
    pack_all<<<(PACK_TOTAL+255)/256, 256, 0, stream>>>(
        gWih, gWhh, Wdyn, l0Whh, l1Wih, l1Whh, l0Wih,
        c1Wf, c1Ws, c2Wf, c2Ws,
        pWih, pWhh, pWdyn, B0h, B1h, P1h, P1l, P2h, P2l, GIh, GIl, cnt, gtot);

    // --- zero output (lstm accumulates via atomics) ---
    (void)hipMemsetAsync(d_out, 0, (size_t)out_size*sizeof(float), stream);

    // --- dst segment build (order-free atomic allocation) ---
    count_kernel<<<(EE+255)/256, 256, 0, stream>>>(ei, cnt);
    alloc_kernel<<<(NN+255)/256, 256, 0, stream>>>(cnt, gtot, offv, curv);
    scatter_kernel<<<(EE+255)/256, 256, 0, stream>>>(ei, ea, curv, recS);

    // --- history encoder (MFMA, pinned weights, 1-barrier loop) ---
    encoder_mfma<<<NN/16, 128, 0, stream>>>(x, Wip, bip, pWih, pWhh, gbih, gbhh, pWdyn, bdyn, hist);

    // --- CGConv 1 ---
    proj_mfma<<<(NN+63)/64, 256, 0, stream>>>(hist, P1h, P1l, Af,Bf,As,Bs);
    cg_agg<<<(NN+3)/4, 256, 0, stream>>>(hist, recS, offv, cnt,
                                         c1Wf,c1bf,c1Ws,c1bs, Af,Bf,As,Bs,
                                         c1g,c1b,c1m,c1v, f1);

    // --- CGConv 2 ---
    proj_mfma<<<(NN+63)/64, 256, 0, stream>>>(f1, P2h, P2l, Af,Bf,As,Bs);
    cg_agg<<<(NN+3)/4, 256, 0, stream>>>(f1, recS, offv, cnt,
                                         c2Wf,c2bf,c2Ws,c2bs, Af,Bf,As,Bs,
                                         c2g,c2b,c2m,c2v, f2);

    // --- target encoding ---
    target_kernel<<<(BB+3)/4, 256, 0, stream>>>(hist, f2, tgt, Wn, bn_, enc);

    // --- LSTM decoder prep (MFMA gi0) ---
    gi0_mfma<<<BB/16, 512, 0, stream>>>(enc, GIh, GIl, l0bih, l0bhh, gi0);

    // --- LSTM decoder (1-barrier t-loop) ---
    lstm_mfma<<<BB/LMB, 512, 0, stream>>>(gi0, B0h, B1h,
                                          l1bih, l1bhh, Wop, bop, (float*)d_out);
}